// Round 1
// baseline (13278.825 us; speedup 1.0000x reference)
//
#include <hip/hip_runtime.h>
#include <math.h>

// ---------------- problem constants ----------------
#define NZ 8
#define T_H 36
#define NVAR 502        // permuted variable count
#define MCON 769
#define NITERS 150
#define SIGMA 1e-6f
#define BIGINF 1e20f

// constraint row offsets
#define R_XLB 9
#define R_XUB 81
#define R_UBOX 153
#define R_UEQ 223
#define R_DYN 275
#define R_SDYN 555
#define R_SLB 590
#define R_SUB 625
#define R_TGT 660
#define R_XSNN 661
#define R_SSNN 733

// global-var offsets (original ordering)
#define NUOFF 288
#define NSOFF 358
#define NXSOFF 394
#define NSSOFF 466

// ws layout (float offsets)
#define OFF_A      0          // A[769][512] permuted cols
#define OFF_CSRV   393728     // [769][12]
#define OFF_CSRC   402956     // [769][12] ints
#define OFF_CSCV   412184     // [502][16]
#define OFF_CSCR   420216     // [502][16] ints
#define OFF_M      428248     // M[502][512]
#define OFF_SINV   685272     // 36 * 14*14
#define OFF_G      692328     // 36 * 14*14 (t>=1 used)
#define OFF_MINV   699384     // Minv[502][512]
#define OFF_L0     956408     // [769]
#define OFF_U0     957177     // [769]

// permuted column: per-timestep blocks [z(8), u(2), s(1), xs(2), ss(1)], t=35 has no u
__device__ __forceinline__ int pcol(int v){
    if (v < 288){ int t = v >> 3, j = v & 7; return 14*t + j; }
    if (v < 358){ int q = v - 288; int t = q >> 1, k = q & 1; return 14*t + 8 + k; }
    if (v < 394){ int t = v - 358; return (t < 35) ? (14*t + 10) : 498; }
    if (v < 466){ int q = v - 394; int t = q >> 1, k = q & 1; return (t < 35) ? (14*t + 11 + k) : (499 + k); }
    int t = v - 466; return (t < 35) ? (14*t + 13) : 501;
}

__device__ __forceinline__ float rho_of(int r){
    if (r <= 8) return 1000.f;
    if (r >= R_UEQ && r < R_SLB) return 1000.f;   // ueq(223..274), dyn(275..554), sdyn(555..589)
    return 1.f;
}

__device__ __forceinline__ float pdiag_p(int p){
    if (p < 490){ int s = p % 14; return (s >= 11) ? 20000.f : 0.f; }
    int s = p - 490; return (s >= 9) ? 20000.f : 0.f;
}

// ---------------- K1: build permuted dense A ----------------
__global__ __launch_bounds__(256) void k_build_A(const float* __restrict__ Az,
                                                 const float* __restrict__ Au,
                                                 const float* __restrict__ ZtoX,
                                                 float* __restrict__ ws){
    float* A = ws + OFF_A;
    int tid = threadIdx.x;
    for (int i = tid; i < 769*512; i += 256) A[i] = 0.f;
    __syncthreads();
    // z0 identity
    for (int i = tid; i < 8; i += 256) A[i*512 + pcol(i)] += 1.f;
    if (tid == 0) A[8*512 + pcol(NSOFF)] += 1.f;
    // xlb/xub ZtoX blocks
    for (int idx = tid; idx < 576; idx += 256){
        int t = idx >> 4, k = (idx >> 3) & 1, j = idx & 7;
        float v = ZtoX[k*8 + j];
        int c = pcol(8*t + j);
        A[(R_XLB + 2*t + k)*512 + c] += v;
        A[(R_XUB + 2*t + k)*512 + c] += v;
    }
    // xs slack in xlb/xub
    for (int idx = tid; idx < 72; idx += 256){
        int c = pcol(NXSOFF + idx);
        A[(R_XLB + idx)*512 + c] += 1.f;
        A[(R_XUB + idx)*512 + c] -= 1.f;
    }
    // ubox
    for (int idx = tid; idx < 70; idx += 256) A[(R_UBOX + idx)*512 + pcol(NUOFF + idx)] += 1.f;
    // ueq (KEEP_T: t in 1..34, t%4!=0)
    for (int idx = tid; idx < 52; idx += 256){
        int i = idx >> 1, kk = idx & 1;
        int t = (i/3)*4 + (i%3) + 1;
        A[(R_UEQ + idx)*512 + pcol(NUOFF + 2*t + kk)]       += 1.f;
        A[(R_UEQ + idx)*512 + pcol(NUOFF + 2*(t-1) + kk)]   -= 1.f;
    }
    // dynamics Az
    for (int idx = tid; idx < 2240; idx += 256){
        int t = idx/64 + 1, rem = idx % 64, j = rem >> 3, k = rem & 7;
        A[(R_DYN + 8*(t-1) + j)*512 + pcol(8*(t-1) + k)] += Az[j*8 + k];
    }
    // dynamics Au
    for (int idx = tid; idx < 560; idx += 256){
        int t = idx/16 + 1, rem = idx % 16, j = rem >> 1, ju = rem & 1;
        A[(R_DYN + 8*(t-1) + j)*512 + pcol(NUOFF + 2*(t-1) + ju)] += Au[j*2 + ju];
    }
    // dynamics -I
    for (int idx = tid; idx < 280; idx += 256){
        int t = (idx >> 3) + 1, j = idx & 7;
        A[(R_DYN + 8*(t-1) + j)*512 + pcol(8*t + j)] -= 1.f;
    }
    // sdyn
    for (int idx = tid; idx < 35; idx += 256){
        int t = idx + 1; int rb = (R_SDYN + idx)*512;
        A[rb + pcol(NSOFF + t)]     += 1.f;
        A[rb + pcol(NSOFF + t - 1)] -= 1.f;
        A[rb + pcol(NUOFF + 2*(t-1))] += -0.05f;   // -0.2/NCC
    }
    // slb / sub
    for (int idx = tid; idx < 35; idx += 256){
        int t = idx + 1;
        A[(R_SLB + idx)*512 + pcol(NSOFF + t)]  += 1.f;
        A[(R_SLB + idx)*512 + pcol(NSSOFF + t)] += 1.f;
        A[(R_SUB + idx)*512 + pcol(NSOFF + t)]  += 1.f;
        A[(R_SUB + idx)*512 + pcol(NSSOFF + t)] -= 1.f;
    }
    if (tid == 0){
        A[R_TGT*512 + pcol(NSOFF + 35)]  += 1.f;
        A[R_TGT*512 + pcol(NSSOFF + 35)] += 1.f;
    }
    for (int idx = tid; idx < 72; idx += 256) A[(R_XSNN + idx)*512 + pcol(NXSOFF + idx)] += 1.f;
    for (int idx = tid; idx < 36; idx += 256) A[(R_SSNN + idx)*512 + pcol(NSSOFF + idx)] += 1.f;
}

// ---------------- K2: CSR(12) / CSC(16) from dense A ----------------
__global__ __launch_bounds__(256) void k_sparse(float* __restrict__ ws){
    const float* A = ws + OFF_A;
    float* crv = ws + OFF_CSRV; int* crc = (int*)(ws + OFF_CSRC);
    float* ccv = ws + OFF_CSCV; int* ccr = (int*)(ws + OFF_CSCR);
    int job = blockIdx.x*256 + threadIdx.x;
    if (job < 769){
        int r = job, n = 0;
        for (int c = 0; c < 502; ++c){
            float v = A[r*512 + c];
            if (v != 0.f && n < 12){ crv[r*12 + n] = v; crc[r*12 + n] = c; ++n; }
        }
        for (; n < 12; ++n){ crv[r*12 + n] = 0.f; crc[r*12 + n] = 0; }
    } else if (job < 1271){
        int c = job - 769, n = 0;
        for (int r = 0; r < 769; ++r){
            float v = A[r*512 + c];
            if (v != 0.f && n < 16){ ccv[c*16 + n] = v; ccr[c*16 + n] = r; ++n; }
        }
        for (; n < 16; ++n){ ccv[c*16 + n] = 0.f; ccr[c*16 + n] = 0; }
    }
}

// ---------------- K3: M = diag(P+sigma) + A^T rho A (permuted) ----------------
__global__ __launch_bounds__(256) void k_build_M(float* __restrict__ ws){
    const float* A = ws + OFF_A;
    const float* ccv = ws + OFF_CSCV; const int* ccr = (const int*)(ws + OFF_CSCR);
    float* M = ws + OFF_M;
    int gid = blockIdx.x*256 + threadIdx.x;
    int i = gid >> 9, j = gid & 511;
    if (j >= 502) return;
    float acc = 0.f;
    #pragma unroll
    for (int s = 0; s < 16; ++s){
        float v = ccv[i*16 + s]; int r = ccr[i*16 + s];
        acc += v * rho_of(r) * A[r*512 + j];
    }
    if (i == j) acc += pdiag_p(i) + SIGMA;
    M[i*512 + j] = acc;
}

// ---------------- K4: block-tridiagonal LDL factor (sequential over t) ----------------
__global__ __launch_bounds__(256) void k_factor(float* __restrict__ ws){
    const float* M = ws + OFF_M;
    float* Gout = ws + OFF_G;
    float* Sout = ws + OFF_SINV;
    __shared__ float Sp[196], Dl[196], Gl[196], fcol[14];
    __shared__ float aug[14*28];
    __shared__ float piv;
    int tid = threadIdx.x;
    for (int t = 0; t < 36; ++t){
        int bs = (t < 35) ? 14 : 12;
        int bo = 14*t;
        for (int idx = tid; idx < bs*bs; idx += 256){ int i = idx/bs, j = idx%bs; aug[i*28 + j] = M[(bo+i)*512 + bo + j]; }
        for (int idx = tid; idx < bs*bs; idx += 256){ int i = idx/bs, j = idx%bs; aug[i*28 + 14 + j] = (i==j) ? 1.f : 0.f; }
        if (t > 0){
            for (int idx = tid; idx < 196; idx += 256){ int i = idx/14, j = idx%14; Dl[idx] = (i < bs) ? M[(bo+i)*512 + (bo-14) + j] : 0.f; }
            __syncthreads();
            for (int idx = tid; idx < 196; idx += 256){
                int i = idx/14, j = idx%14; float a = 0.f;
                #pragma unroll
                for (int k = 0; k < 14; ++k) a += Dl[i*14 + k]*Sp[k*14 + j];
                Gl[idx] = a; Gout[t*196 + idx] = a;
            }
            __syncthreads();
            for (int idx = tid; idx < bs*bs; idx += 256){
                int i = idx/bs, j = idx%bs; float a = 0.f;
                #pragma unroll
                for (int k = 0; k < 14; ++k) a += Gl[i*14 + k]*Dl[j*14 + k];
                aug[i*28 + j] -= a;
            }
        }
        __syncthreads();
        // Gauss-Jordan invert (SPD, no pivoting)
        for (int k = 0; k < bs; ++k){
            if (tid == 0) piv = 1.f/aug[k*28 + k];
            if (tid < bs) fcol[tid] = aug[tid*28 + k];
            __syncthreads();
            for (int j = tid; j < 2*bs; j += 256){ int col = (j < bs) ? j : (14 + j - bs); aug[k*28 + col] *= piv; }
            __syncthreads();
            for (int idx = tid; idx < bs*2*bs; idx += 256){
                int i = idx/(2*bs), jj = idx%(2*bs);
                int col = (jj < bs) ? jj : (14 + jj - bs);
                if (i != k) aug[i*28 + col] -= fcol[i]*aug[k*28 + col];
            }
            __syncthreads();
        }
        for (int idx = tid; idx < 196; idx += 256){
            int i = idx/14, j = idx%14;
            float v = (i < bs && j < bs) ? aug[i*28 + 14 + j] : 0.f;
            Sout[t*196 + idx] = v; Sp[idx] = v;
        }
        __syncthreads();
    }
}

// ---------------- K5: materialize dense Minv (502 unit-RHS solves) ----------------
__global__ __launch_bounds__(256) void k_minv(float* __restrict__ ws){
    const float* G = ws + OFF_G;
    const float* Sinv = ws + OFF_SINV;
    float* Minv = ws + OFF_MINV;
    __shared__ float c[64][504];
    __shared__ float Ga[196], Sb[196];
    int tid = threadIdx.x;
    int p0 = blockIdx.x*64;
    int nr = min(64, 502 - p0);
    // forward: c_0 = b_0
    for (int idx = tid; idx < nr*14; idx += 256){ int q = idx/14, i = idx%14; c[q][i] = ((p0+q) == i) ? 1.f : 0.f; }
    __syncthreads();
    for (int t = 1; t < 36; ++t){
        for (int i = tid; i < 196; i += 256) Ga[i] = G[t*196 + i];
        __syncthreads();
        int bs = (t < 35) ? 14 : 12, bo = 14*t;
        for (int idx = tid; idx < nr*bs; idx += 256){
            int q = idx/bs, i = idx%bs;
            float v = ((p0+q) == (bo+i)) ? 1.f : 0.f;
            #pragma unroll
            for (int j = 0; j < 14; ++j) v -= Ga[i*14 + j]*c[q][bo - 14 + j];
            c[q][bo + i] = v;
        }
        __syncthreads();
    }
    for (int idx = tid; idx < nr*2; idx += 256) c[idx>>1][502 + (idx&1)] = 0.f;
    __syncthreads();
    // backward
    for (int t = 35; t >= 0; --t){
        for (int i = tid; i < 196; i += 256){ Sb[i] = Sinv[t*196 + i]; Ga[i] = (t < 35) ? G[(t+1)*196 + i] : 0.f; }
        __syncthreads();
        int bs = (t < 35) ? 14 : 12, bo = 14*t;
        float v0 = 0.f, v1 = 0.f, v2 = 0.f, v3 = 0.f;
        int n = nr*bs;
        {
            int idx = tid;
            if (idx < n){ int q = idx/bs, i = idx%bs; float v = 0.f;
                #pragma unroll
                for (int j = 0; j < 14; ++j) v += Sb[i*14 + j]*c[q][bo + j];
                if (t < 35){
                    #pragma unroll
                    for (int j = 0; j < 14; ++j) v -= Ga[j*14 + i]*c[q][bo + 14 + j];
                }
                v0 = v; }
            idx += 256;
            if (idx < n){ int q = idx/bs, i = idx%bs; float v = 0.f;
                #pragma unroll
                for (int j = 0; j < 14; ++j) v += Sb[i*14 + j]*c[q][bo + j];
                if (t < 35){
                    #pragma unroll
                    for (int j = 0; j < 14; ++j) v -= Ga[j*14 + i]*c[q][bo + 14 + j];
                }
                v1 = v; }
            idx += 256;
            if (idx < n){ int q = idx/bs, i = idx%bs; float v = 0.f;
                #pragma unroll
                for (int j = 0; j < 14; ++j) v += Sb[i*14 + j]*c[q][bo + j];
                if (t < 35){
                    #pragma unroll
                    for (int j = 0; j < 14; ++j) v -= Ga[j*14 + i]*c[q][bo + 14 + j];
                }
                v2 = v; }
            idx += 256;
            if (idx < n){ int q = idx/bs, i = idx%bs; float v = 0.f;
                #pragma unroll
                for (int j = 0; j < 14; ++j) v += Sb[i*14 + j]*c[q][bo + j];
                if (t < 35){
                    #pragma unroll
                    for (int j = 0; j < 14; ++j) v -= Ga[j*14 + i]*c[q][bo + 14 + j];
                }
                v3 = v; }
        }
        __syncthreads();
        {
            int idx = tid;
            if (idx < n){ int q = idx/bs, i = idx%bs; c[q][bo + i] = v0; }
            idx += 256;
            if (idx < n){ int q = idx/bs, i = idx%bs; c[q][bo + i] = v1; }
            idx += 256;
            if (idx < n){ int q = idx/bs, i = idx%bs; c[q][bo + i] = v2; }
            idx += 256;
            if (idx < n){ int q = idx/bs, i = idx%bs; c[q][bo + i] = v3; }
        }
        __syncthreads();
    }
    for (int q = 0; q < nr; ++q)
        for (int j = tid; j < 502; j += 256)
            Minv[(p0 + q)*512 + j] = c[q][j];
}

// ---------------- K6: batch-uniform bounds ----------------
__global__ __launch_bounds__(256) void k_bounds(const float* __restrict__ Xlb_p, const float* __restrict__ Xub_p,
                                                const float* __restrict__ slb_p, const float* __restrict__ sub_p,
                                                const float* __restrict__ tgt_p, float* __restrict__ ws){
    __shared__ float sc[8];
    float* L0 = ws + OFF_L0; float* U0 = ws + OFF_U0;
    int tid = threadIdx.x;
    if (tid == 0){
        sc[0] = tanhf(Xlb_p[0])*0.5f; sc[1] = tanhf(Xlb_p[1])*0.5f;
        sc[2] = tanhf(Xub_p[0])*0.5f; sc[3] = tanhf(Xub_p[1])*0.5f;
        sc[4] = tanhf(slb_p[0])*0.5f; sc[5] = tanhf(sub_p[0])*0.5f;
        sc[6] = tanhf(tgt_p[0]);
    }
    __syncthreads();
    for (int r = tid; r < 769; r += 256){
        float l = -BIGINF, u = BIGINF;
        if (r < 9){ l = 0.f; u = 0.f; }                      // overridden per-batch in k_admm
        else if (r < R_XUB){ l = -1.f + sc[(r - R_XLB) & 1]; }
        else if (r < R_UBOX){ u = 1.f + sc[2 + ((r - R_XUB) & 1)]; }
        else if (r < R_UEQ){ l = -1.f; u = 1.f; }
        else if (r < R_SLB){ l = 0.f; u = 0.f; }             // ueq, dyn, sdyn
        else if (r < R_SUB){ l = sc[4]; }
        else if (r < R_TGT){ u = 6.f + sc[5]; }
        else if (r == R_TGT){ l = 1.f + sc[6]; }
        else { l = 0.f; }                                    // xsnn, ssnn
        L0[r] = l; U0[r] = u;
    }
}

// ---------------- K7: persistent fused ADMM (150 iterations), 8 batch rows/block ----------------
__global__ __launch_bounds__(256) void k_admm(const float* __restrict__ feat,
                                              const float* __restrict__ XtoZ,
                                              const float* __restrict__ ws,
                                              float* __restrict__ out){
    const float* crv = ws + OFF_CSRV; const int* crc = (const int*)(ws + OFF_CSRC);
    const float* ccv = ws + OFF_CSCV; const int* ccr = (const int*)(ws + OFF_CSCR);
    const float* Minv = ws + OFF_MINV;
    const float* L0 = ws + OFF_L0; const float* U0 = ws + OFF_U0;

    __shared__ __align__(16) float xxT[512][8];   // x, transposed [col][row]
    __shared__ __align__(16) float rhsT[512][8];
    __shared__ __align__(16) float yyT[769][8];
    __shared__ __align__(16) float wwT[769][8];   // w = rho*z - y
    __shared__ float l0s[769], u0s[769];
    __shared__ float zi[8][12];                   // z_init(8) + storage0 at [8]
    __shared__ float pr[8][12];                   // prices9

    int tid = threadIdx.x;
    int b0 = blockIdx.x*8;

    for (int i = tid; i < 769; i += 256){ l0s[i] = L0[i]; u0s[i] = U0[i]; }
    for (int i = tid; i < 512*8; i += 256) (&xxT[0][0])[i] = 0.f;
    for (int i = tid; i < 769*8; i += 256){ (&yyT[0][0])[i] = 0.f; (&wwT[0][0])[i] = 0.f; }
    if (tid < 96){ int r = tid/12, k = tid%12; pr[r][k] = (k < 9) ? feat[(b0+r)*12 + 3 + k] : 0.f; }
    if (tid < 8){
        float s0 = feat[(b0+tid)*12 + 0], s1 = feat[(b0+tid)*12 + 1];
        #pragma unroll
        for (int j = 0; j < 8; ++j) zi[tid][j] = s0*XtoZ[j*2 + 0] + s1*XtoZ[j*2 + 1];
        zi[tid][8] = feat[(b0+tid)*12 + 2];
    }
    __syncthreads();

    for (int it = 0; it < NITERS; ++it){
        // -------- phase A: rhs = sigma*x - q + w@A (CSC gather) --------
        for (int c = tid; c < 502; c += 256){
            float rv[8];
            const float4 xa = *(const float4*)&xxT[c][0];
            const float4 xb = *(const float4*)&xxT[c][4];
            rv[0] = SIGMA*xa.x; rv[1] = SIGMA*xa.y; rv[2] = SIGMA*xa.z; rv[3] = SIGMA*xa.w;
            rv[4] = SIGMA*xb.x; rv[5] = SIGMA*xb.y; rv[6] = SIGMA*xb.z; rv[7] = SIGMA*xb.w;
            int t14 = c/14, s14 = c - t14*14;
            if (c < 490 && s14 == 9){   // q lives at u_{t,1} -> permuted col 14t+9
                int pi = t14 >> 2;
                #pragma unroll
                for (int r = 0; r < 8; ++r) rv[r] -= pr[r][pi];
            }
            for (int s = 0; s < 16; ++s){
                float v = ccv[c*16 + s]; int rr = ccr[c*16 + s];
                const float4 wa = *(const float4*)&wwT[rr][0];
                const float4 wb = *(const float4*)&wwT[rr][4];
                rv[0] += v*wa.x; rv[1] += v*wa.y; rv[2] += v*wa.z; rv[3] += v*wa.w;
                rv[4] += v*wb.x; rv[5] += v*wb.y; rv[6] += v*wb.z; rv[7] += v*wb.w;
            }
            *(float4*)&rhsT[c][0] = make_float4(rv[0], rv[1], rv[2], rv[3]);
            *(float4*)&rhsT[c][4] = make_float4(rv[4], rv[5], rv[6], rv[7]);
        }
        __syncthreads();
        // -------- GEMM: x = rhs @ Minv --------
        {
            int c0 = tid, c1 = tid + 256;
            bool has1 = (c1 < 502);
            float a0[8] = {0,0,0,0,0,0,0,0};
            float a1[8] = {0,0,0,0,0,0,0,0};
            #pragma unroll 4
            for (int k = 0; k < 502; ++k){
                const float4 ra = *(const float4*)&rhsT[k][0];
                const float4 rb = *(const float4*)&rhsT[k][4];
                float m0 = Minv[k*512 + c0];
                a0[0] += ra.x*m0; a0[1] += ra.y*m0; a0[2] += ra.z*m0; a0[3] += ra.w*m0;
                a0[4] += rb.x*m0; a0[5] += rb.y*m0; a0[6] += rb.z*m0; a0[7] += rb.w*m0;
                if (has1){
                    float m1 = Minv[k*512 + c1];
                    a1[0] += ra.x*m1; a1[1] += ra.y*m1; a1[2] += ra.z*m1; a1[3] += ra.w*m1;
                    a1[4] += rb.x*m1; a1[5] += rb.y*m1; a1[6] += rb.z*m1; a1[7] += rb.w*m1;
                }
            }
            *(float4*)&xxT[c0][0] = make_float4(a0[0], a0[1], a0[2], a0[3]);
            *(float4*)&xxT[c0][4] = make_float4(a0[4], a0[5], a0[6], a0[7]);
            if (has1){
                *(float4*)&xxT[c1][0] = make_float4(a1[0], a1[1], a1[2], a1[3]);
                *(float4*)&xxT[c1][4] = make_float4(a1[4], a1[5], a1[6], a1[7]);
            }
        }
        __syncthreads();
        // -------- phase B: Ax (CSR), z = clip, y update, w update --------
        for (int rr = tid; rr < 769; rr += 256){
            float rho = rho_of(rr);
            float rinv = 1.f/rho;
            float ax[8] = {0,0,0,0,0,0,0,0};
            for (int s = 0; s < 12; ++s){
                float v = crv[rr*12 + s]; int cc = crc[rr*12 + s];
                const float4 xa = *(const float4*)&xxT[cc][0];
                const float4 xb = *(const float4*)&xxT[cc][4];
                ax[0] += v*xa.x; ax[1] += v*xa.y; ax[2] += v*xa.z; ax[3] += v*xa.w;
                ax[4] += v*xb.x; ax[5] += v*xb.y; ax[6] += v*xb.z; ax[7] += v*xb.w;
            }
            float lb = 0.f, ub = 0.f;
            if (rr >= 9){ lb = l0s[rr]; ub = u0s[rr]; }
            const float4 ya = *(const float4*)&yyT[rr][0];
            const float4 yb = *(const float4*)&yyT[rr][4];
            float yv[8] = {ya.x, ya.y, ya.z, ya.w, yb.x, yb.y, yb.z, yb.w};
            float wo[8];
            #pragma unroll
            for (int r = 0; r < 8; ++r){
                float li = (rr < 9) ? zi[r][rr] : lb;
                float ui = (rr < 9) ? zi[r][rr] : ub;
                float vv = ax[r] + yv[r]*rinv;
                float z = fminf(fmaxf(vv, li), ui);
                float yn = yv[r] + rho*(ax[r] - z);
                yv[r] = yn;
                wo[r] = rho*z - yn;
            }
            *(float4*)&yyT[rr][0] = make_float4(yv[0], yv[1], yv[2], yv[3]);
            *(float4*)&yyT[rr][4] = make_float4(yv[4], yv[5], yv[6], yv[7]);
            *(float4*)&wwT[rr][0] = make_float4(wo[0], wo[1], wo[2], wo[3]);
            *(float4*)&wwT[rr][4] = make_float4(wo[4], wo[5], wo[6], wo[7]);
        }
        __syncthreads();
    }
    // mu = x[:, NUOFF:NUOFF+2] -> permuted cols 8,9
    if (tid < 16){ int r = tid >> 1, k = tid & 1; out[(b0 + r)*2 + k] = xxT[8 + k][r]; }
}

// ---------------- K8: critic MLP ----------------
__global__ __launch_bounds__(64) void k_critic(const float* __restrict__ feat,
    const float* __restrict__ Ws,  const float* __restrict__ bs_,
    const float* __restrict__ Wst, const float* __restrict__ bst,
    const float* __restrict__ Wipr,const float* __restrict__ bipr,
    const float* __restrict__ Wp,  const float* __restrict__ bp,
    const float* __restrict__ Ws1, const float* __restrict__ bs1,
    const float* __restrict__ Wst1,const float* __restrict__ bst1,
    const float* __restrict__ Wipr1,const float* __restrict__ bipr1,
    const float* __restrict__ Wp1, const float* __restrict__ bp1,
    const float* __restrict__ Wf1, const float* __restrict__ bf1,
    const float* __restrict__ Wf2, const float* __restrict__ bf2,
    float* __restrict__ out){
    __shared__ float hL[64][65];
    __shared__ float h2L[64][65];
    int tid = threadIdx.x;
    int b = blockIdx.x*64 + tid;
    const float* f = feat + b*12;
    float st0 = f[0], st1 = f[1], sg = f[2];
    float p[9];
    #pragma unroll
    for (int j = 0; j < 9; ++j) p[j] = f[3 + j];
    float pmx = p[0], pmn = p[0];
    #pragma unroll
    for (int j = 1; j < 9; ++j){ pmx = fmaxf(pmx, p[j]); pmn = fminf(pmn, p[j]); }
    float t1[24], t2[8];
    // hs: 2 -> 24 -> 24
    #pragma unroll
    for (int o = 0; o < 24; ++o) t1[o] = fmaxf(0.f, st0*Ws[o*2] + st1*Ws[o*2 + 1] + bs_[o]);
    #pragma unroll
    for (int o = 0; o < 24; ++o){ float a = bs1[o];
        #pragma unroll
        for (int j = 0; j < 24; ++j) a += t1[j]*Ws1[o*24 + j];
        hL[tid][o] = fmaxf(0.f, a); }
    // hst: 1 -> 8 -> 8
    #pragma unroll
    for (int o = 0; o < 8; ++o) t2[o] = fmaxf(0.f, sg*Wst[o] + bst[o]);
    #pragma unroll
    for (int o = 0; o < 8; ++o){ float a = bst1[o];
        #pragma unroll
        for (int j = 0; j < 8; ++j) a += t2[j]*Wst1[o*8 + j];
        hL[tid][24 + o] = fmaxf(0.f, a); }
    // hi: 2 -> 8 -> 8
    float i1 = pmx - pmn;
    #pragma unroll
    for (int o = 0; o < 8; ++o) t2[o] = fmaxf(0.f, p[0]*Wipr[o*2] + i1*Wipr[o*2 + 1] + bipr[o]);
    #pragma unroll
    for (int o = 0; o < 8; ++o){ float a = bipr1[o];
        #pragma unroll
        for (int j = 0; j < 8; ++j) a += t2[j]*Wipr1[o*8 + j];
        hL[tid][32 + o] = fmaxf(0.f, a); }
    // hp: 9 -> 24 -> 24
    #pragma unroll
    for (int o = 0; o < 24; ++o){ float a = bp[o];
        #pragma unroll
        for (int j = 0; j < 9; ++j) a += p[j]*Wp[o*9 + j];
        t1[o] = fmaxf(0.f, a); }
    #pragma unroll
    for (int o = 0; o < 24; ++o){ float a = bp1[o];
        #pragma unroll
        for (int j = 0; j < 24; ++j) a += t1[j]*Wp1[o*24 + j];
        hL[tid][40 + o] = fmaxf(0.f, a); }
    // f1, f2: 64 -> 64 -> 64
    for (int o = 0; o < 64; ++o){ float a = bf1[o];
        for (int j = 0; j < 64; ++j) a += hL[tid][j]*Wf1[o*64 + j];
        h2L[tid][o] = fmaxf(0.f, a); }
    for (int o = 0; o < 64; ++o){ float a = bf2[o];
        for (int j = 0; j < 64; ++j) a += h2L[tid][j]*Wf2[o*64 + j];
        out[2048 + b*64 + o] = fmaxf(0.f, a); }
}

extern "C" void kernel_launch(void* const* d_in, const int* in_sizes, int n_in,
                              void* d_out, int out_size, void* d_ws, size_t ws_size,
                              hipStream_t stream){
    (void)in_sizes; (void)n_in; (void)out_size; (void)ws_size;
    const float* feat  = (const float*)d_in[0];
    const float* Xlb_p = (const float*)d_in[1];
    const float* Xub_p = (const float*)d_in[2];
    const float* slb_p = (const float*)d_in[3];
    const float* sub_p = (const float*)d_in[4];
    const float* tgt_p = (const float*)d_in[5];
    const float* Az    = (const float*)d_in[6];
    const float* Au    = (const float*)d_in[7];
    const float* ZtoX  = (const float*)d_in[8];
    const float* XtoZ  = (const float*)d_in[9];
    float* ws  = (float*)d_ws;
    float* out = (float*)d_out;

    hipLaunchKernelGGL(k_build_A, dim3(1),    dim3(256), 0, stream, Az, Au, ZtoX, ws);
    hipLaunchKernelGGL(k_sparse,  dim3(5),    dim3(256), 0, stream, ws);
    hipLaunchKernelGGL(k_build_M, dim3(1004), dim3(256), 0, stream, ws);
    hipLaunchKernelGGL(k_factor,  dim3(1),    dim3(256), 0, stream, ws);
    hipLaunchKernelGGL(k_minv,    dim3(8),    dim3(256), 0, stream, ws);
    hipLaunchKernelGGL(k_bounds,  dim3(1),    dim3(256), 0, stream, Xlb_p, Xub_p, slb_p, sub_p, tgt_p, ws);
    hipLaunchKernelGGL(k_admm,    dim3(128),  dim3(256), 0, stream, feat, XtoZ, ws, out);
    hipLaunchKernelGGL(k_critic,  dim3(16),   dim3(64),  0, stream, feat,
        (const float*)d_in[10], (const float*)d_in[11], (const float*)d_in[12], (const float*)d_in[13],
        (const float*)d_in[14], (const float*)d_in[15], (const float*)d_in[16], (const float*)d_in[17],
        (const float*)d_in[18], (const float*)d_in[19], (const float*)d_in[20], (const float*)d_in[21],
        (const float*)d_in[22], (const float*)d_in[23], (const float*)d_in[24], (const float*)d_in[25],
        (const float*)d_in[26], (const float*)d_in[27], (const float*)d_in[28], (const float*)d_in[29],
        out);
}

// Round 3
// 4591.896 us; speedup vs baseline: 2.8918x; 2.8918x over previous
//
#include <hip/hip_runtime.h>
#include <math.h>

// ---------------- problem constants ----------------
#define NZ 8
#define T_H 36
#define NVAR 502        // permuted variable count
#define MCON 769
#define NITERS 150
#define SIGMA 1e-6f
#define BIGINF 1e20f
#define ROWS 4          // batch rows per ADMM block

// constraint row offsets
#define R_XLB 9
#define R_XUB 81
#define R_UBOX 153
#define R_UEQ 223
#define R_DYN 275
#define R_SDYN 555
#define R_SLB 590
#define R_SUB 625
#define R_TGT 660
#define R_XSNN 661
#define R_SSNN 733

// global-var offsets (original ordering)
#define NUOFF 288
#define NSOFF 358
#define NXSOFF 394
#define NSSOFF 466

// ws layout (float offsets)
#define OFF_A      0          // A[769][512] permuted cols
#define OFF_CSRV   393728     // [769][12]
#define OFF_CSRC   402956     // [769][12] ints
#define OFF_CSCV   412184     // [502][16]
#define OFF_CSCR   420216     // [502][16] ints
#define OFF_M      428248     // M[502][512]
#define OFF_SINV   685272     // 36 * 14*14
#define OFF_G      692328     // 36 * 14*14 (t>=1 used)
#define OFF_MINV   699384     // Minv[502][512]
#define OFF_L0     956408     // [769]
#define OFF_U0     957177     // [769]

// permuted column: per-timestep blocks [z(8), u(2), s(1), xs(2), ss(1)], t=35 has no u
__device__ __forceinline__ int pcol(int v){
    if (v < 288){ int t = v >> 3, j = v & 7; return 14*t + j; }
    if (v < 358){ int q = v - 288; int t = q >> 1, k = q & 1; return 14*t + 8 + k; }
    if (v < 394){ int t = v - 358; return (t < 35) ? (14*t + 10) : 498; }
    if (v < 466){ int q = v - 394; int t = q >> 1, k = q & 1; return (t < 35) ? (14*t + 11 + k) : (499 + k); }
    int t = v - 466; return (t < 35) ? (14*t + 13) : 501;
}

__device__ __forceinline__ float rho_of(int r){
    if (r <= 8) return 1000.f;
    if (r >= R_UEQ && r < R_SLB) return 1000.f;   // ueq(223..274), dyn(275..554), sdyn(555..589)
    return 1.f;
}

__device__ __forceinline__ float pdiag_p(int p){
    if (p < 490){ int s = p % 14; return (s >= 11) ? 20000.f : 0.f; }
    int s = p - 490; return (s >= 9) ? 20000.f : 0.f;
}

// ---------------- K1: build permuted dense A ----------------
__global__ __launch_bounds__(256) void k_build_A(const float* __restrict__ Az,
                                                 const float* __restrict__ Au,
                                                 const float* __restrict__ ZtoX,
                                                 float* __restrict__ ws){
    float* A = ws + OFF_A;
    int tid = threadIdx.x;
    for (int i = tid; i < 769*512; i += 256) A[i] = 0.f;
    __syncthreads();
    // z0 identity
    for (int i = tid; i < 8; i += 256) A[i*512 + pcol(i)] += 1.f;
    if (tid == 0) A[8*512 + pcol(NSOFF)] += 1.f;
    // xlb/xub ZtoX blocks
    for (int idx = tid; idx < 576; idx += 256){
        int t = idx >> 4, k = (idx >> 3) & 1, j = idx & 7;
        float v = ZtoX[k*8 + j];
        int c = pcol(8*t + j);
        A[(R_XLB + 2*t + k)*512 + c] += v;
        A[(R_XUB + 2*t + k)*512 + c] += v;
    }
    // xs slack in xlb/xub
    for (int idx = tid; idx < 72; idx += 256){
        int c = pcol(NXSOFF + idx);
        A[(R_XLB + idx)*512 + c] += 1.f;
        A[(R_XUB + idx)*512 + c] -= 1.f;
    }
    // ubox
    for (int idx = tid; idx < 70; idx += 256) A[(R_UBOX + idx)*512 + pcol(NUOFF + idx)] += 1.f;
    // ueq (KEEP_T: t in 1..34, t%4!=0)
    for (int idx = tid; idx < 52; idx += 256){
        int i = idx >> 1, kk = idx & 1;
        int t = (i/3)*4 + (i%3) + 1;
        A[(R_UEQ + idx)*512 + pcol(NUOFF + 2*t + kk)]       += 1.f;
        A[(R_UEQ + idx)*512 + pcol(NUOFF + 2*(t-1) + kk)]   -= 1.f;
    }
    // dynamics Az
    for (int idx = tid; idx < 2240; idx += 256){
        int t = idx/64 + 1, rem = idx % 64, j = rem >> 3, k = rem & 7;
        A[(R_DYN + 8*(t-1) + j)*512 + pcol(8*(t-1) + k)] += Az[j*8 + k];
    }
    // dynamics Au
    for (int idx = tid; idx < 560; idx += 256){
        int t = idx/16 + 1, rem = idx % 16, j = rem >> 1, ju = rem & 1;
        A[(R_DYN + 8*(t-1) + j)*512 + pcol(NUOFF + 2*(t-1) + ju)] += Au[j*2 + ju];
    }
    // dynamics -I
    for (int idx = tid; idx < 280; idx += 256){
        int t = (idx >> 3) + 1, j = idx & 7;
        A[(R_DYN + 8*(t-1) + j)*512 + pcol(8*t + j)] -= 1.f;
    }
    // sdyn
    for (int idx = tid; idx < 35; idx += 256){
        int t = idx + 1; int rb = (R_SDYN + idx)*512;
        A[rb + pcol(NSOFF + t)]     += 1.f;
        A[rb + pcol(NSOFF + t - 1)] -= 1.f;
        A[rb + pcol(NUOFF + 2*(t-1))] += -0.05f;   // -0.2/NCC
    }
    // slb / sub
    for (int idx = tid; idx < 35; idx += 256){
        int t = idx + 1;
        A[(R_SLB + idx)*512 + pcol(NSOFF + t)]  += 1.f;
        A[(R_SLB + idx)*512 + pcol(NSSOFF + t)] += 1.f;
        A[(R_SUB + idx)*512 + pcol(NSOFF + t)]  += 1.f;
        A[(R_SUB + idx)*512 + pcol(NSSOFF + t)] -= 1.f;
    }
    if (tid == 0){
        A[R_TGT*512 + pcol(NSOFF + 35)]  += 1.f;
        A[R_TGT*512 + pcol(NSSOFF + 35)] += 1.f;
    }
    for (int idx = tid; idx < 72; idx += 256) A[(R_XSNN + idx)*512 + pcol(NXSOFF + idx)] += 1.f;
    for (int idx = tid; idx < 36; idx += 256) A[(R_SSNN + idx)*512 + pcol(NSSOFF + idx)] += 1.f;
}

// ---------------- K2: CSR(12) / CSC(16) from dense A ----------------
__global__ __launch_bounds__(256) void k_sparse(float* __restrict__ ws){
    const float* A = ws + OFF_A;
    float* crv = ws + OFF_CSRV; int* crc = (int*)(ws + OFF_CSRC);
    float* ccv = ws + OFF_CSCV; int* ccr = (int*)(ws + OFF_CSCR);
    int job = blockIdx.x*256 + threadIdx.x;
    if (job < 769){
        int r = job, n = 0;
        for (int c = 0; c < 502; ++c){
            float v = A[r*512 + c];
            if (v != 0.f && n < 12){ crv[r*12 + n] = v; crc[r*12 + n] = c; ++n; }
        }
        for (; n < 12; ++n){ crv[r*12 + n] = 0.f; crc[r*12 + n] = 0; }
    } else if (job < 1271){
        int c = job - 769, n = 0;
        for (int r = 0; r < 769; ++r){
            float v = A[r*512 + c];
            if (v != 0.f && n < 16){ ccv[c*16 + n] = v; ccr[c*16 + n] = r; ++n; }
        }
        for (; n < 16; ++n){ ccv[c*16 + n] = 0.f; ccr[c*16 + n] = 0; }
    }
}

// ---------------- K3: M = diag(P+sigma) + A^T rho A (permuted) ----------------
__global__ __launch_bounds__(256) void k_build_M(float* __restrict__ ws){
    const float* A = ws + OFF_A;
    const float* ccv = ws + OFF_CSCV; const int* ccr = (const int*)(ws + OFF_CSCR);
    float* M = ws + OFF_M;
    int gid = blockIdx.x*256 + threadIdx.x;
    int i = gid >> 9, j = gid & 511;
    if (j >= 502) return;
    float acc = 0.f;
    #pragma unroll
    for (int s = 0; s < 16; ++s){
        float v = ccv[i*16 + s]; int r = ccr[i*16 + s];
        acc += v * rho_of(r) * A[r*512 + j];
    }
    if (i == j) acc += pdiag_p(i) + SIGMA;
    M[i*512 + j] = acc;
}

// ---------------- K4: block-tridiagonal LDL factor (sequential over t) ----------------
__global__ __launch_bounds__(256) void k_factor(float* __restrict__ ws){
    const float* M = ws + OFF_M;
    float* Gout = ws + OFF_G;
    float* Sout = ws + OFF_SINV;
    __shared__ float Sp[196], Dl[196], Gl[196], fcol[14];
    __shared__ float aug[14*28];
    __shared__ float piv;
    int tid = threadIdx.x;
    for (int t = 0; t < 36; ++t){
        int bs = (t < 35) ? 14 : 12;
        int bo = 14*t;
        for (int idx = tid; idx < bs*bs; idx += 256){ int i = idx/bs, j = idx%bs; aug[i*28 + j] = M[(bo+i)*512 + bo + j]; }
        for (int idx = tid; idx < bs*bs; idx += 256){ int i = idx/bs, j = idx%bs; aug[i*28 + 14 + j] = (i==j) ? 1.f : 0.f; }
        if (t > 0){
            for (int idx = tid; idx < 196; idx += 256){ int i = idx/14, j = idx%14; Dl[idx] = (i < bs) ? M[(bo+i)*512 + (bo-14) + j] : 0.f; }
            __syncthreads();
            for (int idx = tid; idx < 196; idx += 256){
                int i = idx/14, j = idx%14; float a = 0.f;
                #pragma unroll
                for (int k = 0; k < 14; ++k) a += Dl[i*14 + k]*Sp[k*14 + j];
                Gl[idx] = a; Gout[t*196 + idx] = a;
            }
            __syncthreads();
            for (int idx = tid; idx < bs*bs; idx += 256){
                int i = idx/bs, j = idx%bs; float a = 0.f;
                #pragma unroll
                for (int k = 0; k < 14; ++k) a += Gl[i*14 + k]*Dl[j*14 + k];
                aug[i*28 + j] -= a;
            }
        }
        __syncthreads();
        // Gauss-Jordan invert (SPD, no pivoting)
        for (int k = 0; k < bs; ++k){
            if (tid == 0) piv = 1.f/aug[k*28 + k];
            if (tid < bs) fcol[tid] = aug[tid*28 + k];
            __syncthreads();
            for (int j = tid; j < 2*bs; j += 256){ int col = (j < bs) ? j : (14 + j - bs); aug[k*28 + col] *= piv; }
            __syncthreads();
            for (int idx = tid; idx < bs*2*bs; idx += 256){
                int i = idx/(2*bs), jj = idx%(2*bs);
                int col = (jj < bs) ? jj : (14 + jj - bs);
                if (i != k) aug[i*28 + col] -= fcol[i]*aug[k*28 + col];
            }
            __syncthreads();
        }
        for (int idx = tid; idx < 196; idx += 256){
            int i = idx/14, j = idx%14;
            float v = (i < bs && j < bs) ? aug[i*28 + 14 + j] : 0.f;
            Sout[t*196 + idx] = v; Sp[idx] = v;
        }
        __syncthreads();
    }
}

// ---------------- K5: materialize dense Minv (502 unit-RHS solves) ----------------
__global__ __launch_bounds__(256) void k_minv(float* __restrict__ ws){
    const float* G = ws + OFF_G;
    const float* Sinv = ws + OFF_SINV;
    float* Minv = ws + OFF_MINV;
    __shared__ float c[64][504];
    __shared__ float Ga[196], Sb[196];
    int tid = threadIdx.x;
    int p0 = blockIdx.x*64;
    int nr = min(64, 502 - p0);
    // forward: c_0 = b_0
    for (int idx = tid; idx < nr*14; idx += 256){ int q = idx/14, i = idx%14; c[q][i] = ((p0+q) == i) ? 1.f : 0.f; }
    __syncthreads();
    for (int t = 1; t < 36; ++t){
        for (int i = tid; i < 196; i += 256) Ga[i] = G[t*196 + i];
        __syncthreads();
        int bs = (t < 35) ? 14 : 12, bo = 14*t;
        for (int idx = tid; idx < nr*bs; idx += 256){
            int q = idx/bs, i = idx%bs;
            float v = ((p0+q) == (bo+i)) ? 1.f : 0.f;
            #pragma unroll
            for (int j = 0; j < 14; ++j) v -= Ga[i*14 + j]*c[q][bo - 14 + j];
            c[q][bo + i] = v;
        }
        __syncthreads();
    }
    for (int idx = tid; idx < nr*2; idx += 256) c[idx>>1][502 + (idx&1)] = 0.f;
    __syncthreads();
    // backward
    for (int t = 35; t >= 0; --t){
        for (int i = tid; i < 196; i += 256){ Sb[i] = Sinv[t*196 + i]; Ga[i] = (t < 35) ? G[(t+1)*196 + i] : 0.f; }
        __syncthreads();
        int bs = (t < 35) ? 14 : 12, bo = 14*t;
        float v0 = 0.f, v1 = 0.f, v2 = 0.f, v3 = 0.f;
        int n = nr*bs;
        {
            int idx = tid;
            if (idx < n){ int q = idx/bs, i = idx%bs; float v = 0.f;
                #pragma unroll
                for (int j = 0; j < 14; ++j) v += Sb[i*14 + j]*c[q][bo + j];
                if (t < 35){
                    #pragma unroll
                    for (int j = 0; j < 14; ++j) v -= Ga[j*14 + i]*c[q][bo + 14 + j];
                }
                v0 = v; }
            idx += 256;
            if (idx < n){ int q = idx/bs, i = idx%bs; float v = 0.f;
                #pragma unroll
                for (int j = 0; j < 14; ++j) v += Sb[i*14 + j]*c[q][bo + j];
                if (t < 35){
                    #pragma unroll
                    for (int j = 0; j < 14; ++j) v -= Ga[j*14 + i]*c[q][bo + 14 + j];
                }
                v1 = v; }
            idx += 256;
            if (idx < n){ int q = idx/bs, i = idx%bs; float v = 0.f;
                #pragma unroll
                for (int j = 0; j < 14; ++j) v += Sb[i*14 + j]*c[q][bo + j];
                if (t < 35){
                    #pragma unroll
                    for (int j = 0; j < 14; ++j) v -= Ga[j*14 + i]*c[q][bo + 14 + j];
                }
                v2 = v; }
            idx += 256;
            if (idx < n){ int q = idx/bs, i = idx%bs; float v = 0.f;
                #pragma unroll
                for (int j = 0; j < 14; ++j) v += Sb[i*14 + j]*c[q][bo + j];
                if (t < 35){
                    #pragma unroll
                    for (int j = 0; j < 14; ++j) v -= Ga[j*14 + i]*c[q][bo + 14 + j];
                }
                v3 = v; }
        }
        __syncthreads();
        {
            int idx = tid;
            if (idx < n){ int q = idx/bs, i = idx%bs; c[q][bo + i] = v0; }
            idx += 256;
            if (idx < n){ int q = idx/bs, i = idx%bs; c[q][bo + i] = v1; }
            idx += 256;
            if (idx < n){ int q = idx/bs, i = idx%bs; c[q][bo + i] = v2; }
            idx += 256;
            if (idx < n){ int q = idx/bs, i = idx%bs; c[q][bo + i] = v3; }
        }
        __syncthreads();
    }
    for (int q = 0; q < nr; ++q)
        for (int j = tid; j < 502; j += 256)
            Minv[(p0 + q)*512 + j] = c[q][j];
}

// ---------------- K6: batch-uniform bounds ----------------
__global__ __launch_bounds__(256) void k_bounds(const float* __restrict__ Xlb_p, const float* __restrict__ Xub_p,
                                                const float* __restrict__ slb_p, const float* __restrict__ sub_p,
                                                const float* __restrict__ tgt_p, float* __restrict__ ws){
    __shared__ float sc[8];
    float* L0 = ws + OFF_L0; float* U0 = ws + OFF_U0;
    int tid = threadIdx.x;
    if (tid == 0){
        sc[0] = tanhf(Xlb_p[0])*0.5f; sc[1] = tanhf(Xlb_p[1])*0.5f;
        sc[2] = tanhf(Xub_p[0])*0.5f; sc[3] = tanhf(Xub_p[1])*0.5f;
        sc[4] = tanhf(slb_p[0])*0.5f; sc[5] = tanhf(sub_p[0])*0.5f;
        sc[6] = tanhf(tgt_p[0]);
    }
    __syncthreads();
    for (int r = tid; r < 769; r += 256){
        float l = -BIGINF, u = BIGINF;
        if (r < 9){ l = 0.f; u = 0.f; }                      // overridden per-batch in k_admm
        else if (r < R_XUB){ l = -1.f + sc[(r - R_XLB) & 1]; }
        else if (r < R_UBOX){ u = 1.f + sc[2 + ((r - R_XUB) & 1)]; }
        else if (r < R_UEQ){ l = -1.f; u = 1.f; }
        else if (r < R_SLB){ l = 0.f; u = 0.f; }             // ueq, dyn, sdyn
        else if (r < R_SUB){ l = sc[4]; }
        else if (r < R_TGT){ u = 6.f + sc[5]; }
        else if (r == R_TGT){ l = 1.f + sc[6]; }
        else { l = 0.f; }                                    // xsnn, ssnn
        L0[r] = l; U0[r] = u;
    }
}

// ---------------- K7: persistent fused ADMM (150 iterations), 4 batch rows/block, 512 thr ----------------
__global__ __launch_bounds__(512) void k_admm(const float* __restrict__ feat,
                                              const float* __restrict__ XtoZ,
                                              const float* __restrict__ ws,
                                              float* __restrict__ out){
    const float* crv = ws + OFF_CSRV; const int* crc = (const int*)(ws + OFF_CSRC);
    const float* ccv = ws + OFF_CSCV; const int* ccr = (const int*)(ws + OFF_CSCR);
    const float* Minv = ws + OFF_MINV;
    const float* L0 = ws + OFF_L0; const float* U0 = ws + OFF_U0;

    __shared__ __align__(16) float xxT[512][ROWS];   // x, transposed [col][row]
    __shared__ __align__(16) float rhsT[512][ROWS];
    __shared__ __align__(16) float yyT[769][ROWS];
    __shared__ __align__(16) float wwT[769][ROWS];   // w = rho*z - y
    __shared__ float l0s[769], u0s[769];
    __shared__ float zi[ROWS][12];                   // z_init(8) + storage0 at [8]
    __shared__ float pr[ROWS][12];                   // prices9

    int tid = threadIdx.x;
    int b0 = blockIdx.x*ROWS;

    for (int i = tid; i < 769; i += 512){ l0s[i] = L0[i]; u0s[i] = U0[i]; }
    for (int i = tid; i < 512*ROWS; i += 512) (&xxT[0][0])[i] = 0.f;
    for (int i = tid; i < 769*ROWS; i += 512){ (&yyT[0][0])[i] = 0.f; (&wwT[0][0])[i] = 0.f; }
    if (tid < 12*ROWS){ int r = tid/12, k = tid%12; pr[r][k] = (k < 9) ? feat[(b0+r)*12 + 3 + k] : 0.f; }
    if (tid < ROWS){
        float s0 = feat[(b0+tid)*12 + 0], s1 = feat[(b0+tid)*12 + 1];
        #pragma unroll
        for (int j = 0; j < 8; ++j) zi[tid][j] = s0*XtoZ[j*2 + 0] + s1*XtoZ[j*2 + 1];
        zi[tid][8] = feat[(b0+tid)*12 + 2];
    }
    __syncthreads();

    for (int it = 0; it < NITERS; ++it){
        // -------- phase A: rhs = sigma*x - q + w@A (CSC gather) --------
        if (tid < 502){
            int c = tid;
            float rv[ROWS];
            const float4 xa = *(const float4*)&xxT[c][0];
            rv[0] = SIGMA*xa.x; rv[1] = SIGMA*xa.y; rv[2] = SIGMA*xa.z; rv[3] = SIGMA*xa.w;
            int t14 = c/14, s14 = c - t14*14;
            if (c < 490 && s14 == 9){   // q lives at u_{t,1} -> permuted col 14t+9
                int pi = t14 >> 2;
                #pragma unroll
                for (int r = 0; r < ROWS; ++r) rv[r] -= pr[r][pi];
            }
            #pragma unroll 4
            for (int s = 0; s < 16; ++s){
                float v = ccv[c*16 + s]; int rr = ccr[c*16 + s];
                const float4 wa = *(const float4*)&wwT[rr][0];
                rv[0] += v*wa.x; rv[1] += v*wa.y; rv[2] += v*wa.z; rv[3] += v*wa.w;
            }
            *(float4*)&rhsT[c][0] = make_float4(rv[0], rv[1], rv[2], rv[3]);
        }
        __syncthreads();
        // -------- GEMM: x = rhs @ Minv --------
        if (tid < 502){
            float a0 = 0.f, a1 = 0.f, a2 = 0.f, a3 = 0.f;
            const float* mp = Minv + tid;
            #pragma unroll 8
            for (int k = 0; k < 502; ++k){
                const float4 ra = *(const float4*)&rhsT[k][0];
                float m = mp[k*512];
                a0 += ra.x*m; a1 += ra.y*m; a2 += ra.z*m; a3 += ra.w*m;
            }
            *(float4*)&xxT[tid][0] = make_float4(a0, a1, a2, a3);
        }
        __syncthreads();
        // -------- phase B: Ax (CSR), z = clip, y update, w update --------
        for (int rr = tid; rr < 769; rr += 512){
            float rho = rho_of(rr);
            float rinv = 1.f/rho;
            float ax[ROWS] = {0,0,0,0};
            #pragma unroll 4
            for (int s = 0; s < 12; ++s){
                float v = crv[rr*12 + s]; int cc = crc[rr*12 + s];
                const float4 xa = *(const float4*)&xxT[cc][0];
                ax[0] += v*xa.x; ax[1] += v*xa.y; ax[2] += v*xa.z; ax[3] += v*xa.w;
            }
            float lb = 0.f, ub = 0.f;
            if (rr >= 9){ lb = l0s[rr]; ub = u0s[rr]; }
            const float4 ya = *(const float4*)&yyT[rr][0];
            float yv[ROWS] = {ya.x, ya.y, ya.z, ya.w};
            float wo[ROWS];
            #pragma unroll
            for (int r = 0; r < ROWS; ++r){
                float li = (rr < 9) ? zi[r][rr] : lb;
                float ui = (rr < 9) ? zi[r][rr] : ub;
                float vv = ax[r] + yv[r]*rinv;
                float z = fminf(fmaxf(vv, li), ui);
                float yn = yv[r] + rho*(ax[r] - z);
                yv[r] = yn;
                wo[r] = rho*z - yn;
            }
            *(float4*)&yyT[rr][0] = make_float4(yv[0], yv[1], yv[2], yv[3]);
            *(float4*)&wwT[rr][0] = make_float4(wo[0], wo[1], wo[2], wo[3]);
        }
        __syncthreads();
    }
    // mu = x[:, NUOFF:NUOFF+2] -> permuted cols 8,9
    if (tid < ROWS*2){ int r = tid >> 1, k = tid & 1; out[(b0 + r)*2 + k] = xxT[8 + k][r]; }
}

// ---------------- K8: critic MLP ----------------
__global__ __launch_bounds__(64) void k_critic(const float* __restrict__ feat,
    const float* __restrict__ Ws,  const float* __restrict__ bs_,
    const float* __restrict__ Wst, const float* __restrict__ bst,
    const float* __restrict__ Wipr,const float* __restrict__ bipr,
    const float* __restrict__ Wp,  const float* __restrict__ bp,
    const float* __restrict__ Ws1, const float* __restrict__ bs1,
    const float* __restrict__ Wst1,const float* __restrict__ bst1,
    const float* __restrict__ Wipr1,const float* __restrict__ bipr1,
    const float* __restrict__ Wp1, const float* __restrict__ bp1,
    const float* __restrict__ Wf1, const float* __restrict__ bf1,
    const float* __restrict__ Wf2, const float* __restrict__ bf2,
    float* __restrict__ out){
    __shared__ float hL[64][65];
    __shared__ float h2L[64][65];
    int tid = threadIdx.x;
    int b = blockIdx.x*64 + tid;
    const float* f = feat + b*12;
    float st0 = f[0], st1 = f[1], sg = f[2];
    float p[9];
    #pragma unroll
    for (int j = 0; j < 9; ++j) p[j] = f[3 + j];
    float pmx = p[0], pmn = p[0];
    #pragma unroll
    for (int j = 1; j < 9; ++j){ pmx = fmaxf(pmx, p[j]); pmn = fminf(pmn, p[j]); }
    float t1[24], t2[8];
    // hs: 2 -> 24 -> 24
    #pragma unroll
    for (int o = 0; o < 24; ++o) t1[o] = fmaxf(0.f, st0*Ws[o*2] + st1*Ws[o*2 + 1] + bs_[o]);
    #pragma unroll
    for (int o = 0; o < 24; ++o){ float a = bs1[o];
        #pragma unroll
        for (int j = 0; j < 24; ++j) a += t1[j]*Ws1[o*24 + j];
        hL[tid][o] = fmaxf(0.f, a); }
    // hst: 1 -> 8 -> 8
    #pragma unroll
    for (int o = 0; o < 8; ++o) t2[o] = fmaxf(0.f, sg*Wst[o] + bst[o]);
    #pragma unroll
    for (int o = 0; o < 8; ++o){ float a = bst1[o];
        #pragma unroll
        for (int j = 0; j < 8; ++j) a += t2[j]*Wst1[o*8 + j];
        hL[tid][24 + o] = fmaxf(0.f, a); }
    // hi: 2 -> 8 -> 8
    float i1 = pmx - pmn;
    #pragma unroll
    for (int o = 0; o < 8; ++o) t2[o] = fmaxf(0.f, p[0]*Wipr[o*2] + i1*Wipr[o*2 + 1] + bipr[o]);
    #pragma unroll
    for (int o = 0; o < 8; ++o){ float a = bipr1[o];
        #pragma unroll
        for (int j = 0; j < 8; ++j) a += t2[j]*Wipr1[o*8 + j];
        hL[tid][32 + o] = fmaxf(0.f, a); }
    // hp: 9 -> 24 -> 24
    #pragma unroll
    for (int o = 0; o < 24; ++o){ float a = bp[o];
        #pragma unroll
        for (int j = 0; j < 9; ++j) a += p[j]*Wp[o*9 + j];
        t1[o] = fmaxf(0.f, a); }
    #pragma unroll
    for (int o = 0; o < 24; ++o){ float a = bp1[o];
        #pragma unroll
        for (int j = 0; j < 24; ++j) a += t1[j]*Wp1[o*24 + j];
        hL[tid][40 + o] = fmaxf(0.f, a); }
    // f1, f2: 64 -> 64 -> 64
    for (int o = 0; o < 64; ++o){ float a = bf1[o];
        for (int j = 0; j < 64; ++j) a += hL[tid][j]*Wf1[o*64 + j];
        h2L[tid][o] = fmaxf(0.f, a); }
    for (int o = 0; o < 64; ++o){ float a = bf2[o];
        for (int j = 0; j < 64; ++j) a += h2L[tid][j]*Wf2[o*64 + j];
        out[2048 + b*64 + o] = fmaxf(0.f, a); }
}

extern "C" void kernel_launch(void* const* d_in, const int* in_sizes, int n_in,
                              void* d_out, int out_size, void* d_ws, size_t ws_size,
                              hipStream_t stream){
    (void)in_sizes; (void)n_in; (void)out_size; (void)ws_size;
    const float* feat  = (const float*)d_in[0];
    const float* Xlb_p = (const float*)d_in[1];
    const float* Xub_p = (const float*)d_in[2];
    const float* slb_p = (const float*)d_in[3];
    const float* sub_p = (const float*)d_in[4];
    const float* tgt_p = (const float*)d_in[5];
    const float* Az    = (const float*)d_in[6];
    const float* Au    = (const float*)d_in[7];
    const float* ZtoX  = (const float*)d_in[8];
    const float* XtoZ  = (const float*)d_in[9];
    float* ws  = (float*)d_ws;
    float* out = (float*)d_out;

    hipLaunchKernelGGL(k_build_A, dim3(1),    dim3(256), 0, stream, Az, Au, ZtoX, ws);
    hipLaunchKernelGGL(k_sparse,  dim3(5),    dim3(256), 0, stream, ws);
    hipLaunchKernelGGL(k_build_M, dim3(1004), dim3(256), 0, stream, ws);
    hipLaunchKernelGGL(k_factor,  dim3(1),    dim3(256), 0, stream, ws);
    hipLaunchKernelGGL(k_minv,    dim3(8),    dim3(256), 0, stream, ws);
    hipLaunchKernelGGL(k_bounds,  dim3(1),    dim3(256), 0, stream, Xlb_p, Xub_p, slb_p, sub_p, tgt_p, ws);
    hipLaunchKernelGGL(k_admm,    dim3(256),  dim3(512), 0, stream, feat, XtoZ, ws, out);
    hipLaunchKernelGGL(k_critic,  dim3(16),   dim3(64),  0, stream, feat,
        (const float*)d_in[10], (const float*)d_in[11], (const float*)d_in[12], (const float*)d_in[13],
        (const float*)d_in[14], (const float*)d_in[15], (const float*)d_in[16], (const float*)d_in[17],
        (const float*)d_in[18], (const float*)d_in[19], (const float*)d_in[20], (const float*)d_in[21],
        (const float*)d_in[22], (const float*)d_in[23], (const float*)d_in[24], (const float*)d_in[25],
        (const float*)d_in[26], (const float*)d_in[27], (const float*)d_in[28], (const float*)d_in[29],
        out);
}